// Round 12
// baseline (165.776 us; speedup 1.0000x reference)
//
#include <hip/hip_runtime.h>
#include <stdint.h>

typedef unsigned short u16;
typedef __attribute__((ext_vector_type(8))) short bf16x8;    // 8 bf16 in 4 VGPRs
typedef __attribute__((ext_vector_type(4))) float floatx4;
typedef __attribute__((ext_vector_type(16))) float floatx16;
typedef __attribute__((ext_vector_type(4))) unsigned uintx4;

#define MFMA16(a, b, c) __builtin_amdgcn_mfma_f32_16x16x32_bf16(a, b, c, 0, 0, 0)
#define MFMA32(a, b, c) __builtin_amdgcn_mfma_f32_32x32x16_bf16(a, b, c, 0, 0, 0)
#define MEMFENCE asm volatile("" ::: "memory")

#if __has_builtin(__builtin_amdgcn_exp2f)
#define EXP2(x) __builtin_amdgcn_exp2f(x)
#else
#define EXP2(x) __expf(0.6931471805599453f * (x))
#endif

__device__ __forceinline__ u16 f2bf(float f) {   // round-to-nearest-even
  unsigned u = __builtin_bit_cast(unsigned, f);
  return (u16)((u + 0x7FFFu + ((u >> 16) & 1u)) >> 16);
}
__device__ __forceinline__ unsigned pkbf(float a, float b) {  // round-half-up pack
  unsigned ua = __builtin_bit_cast(unsigned, a);
  unsigned ub = __builtin_bit_cast(unsigned, b);
  return ((ua + 0x8000u) >> 16) | ((ub + 0x8000u) & 0xFFFF0000u);
}
__device__ __forceinline__ float bf2f(u16 v) {
  return __builtin_bit_cast(float, (unsigned)v << 16);
}

// async global->LDS, 16B/lane. LDS dest = wave-uniform base + lane*16 (HW).
__device__ __forceinline__ void glds16(void* lds, const void* g) {
  __builtin_amdgcn_global_load_lds((const __attribute__((address_space(1))) void*)g,
                                   (__attribute__((address_space(3))) void*)lds,
                                   16, 0, 0);
}

// Fragment-major layouts (u16 strides):
//   Kf[bh][kt][kk][m][h][l31][8]: bh:131072, kt:4096, kk:1024, m:512, h:256, l31:8
//     lane(l31,h) of chunk (kk,m) = K[kt*64 + m*32 + l31][kk*16 + h*8 .. +8]
//   Vf[bh][kt][c][dt][h][l31][8]: bh:131072, kt:4096, c:1024, dt:512, h:256, l31:8
//     lane(l31,h) of chunk (c,dt) = V^T[dt*32 + l31][kt*64 + c*16 + h*8 .. +8]
// => attn fragment load = ONE contiguous 1KB wave read (global_load_dwordx4).

// ---------------------------------------------------------------- convert
__global__ __launch_bounds__(256) void cvt_all(
    const float* __restrict__ x, const float* __restrict__ w0,
    const float* __restrict__ w1, const float* __restrict__ w2,
    u16* __restrict__ xb, u16* __restrict__ Wb) {
  const int bid = blockIdx.x;
  const float* src;
  u16* dst;
  int i;
  if (bid < 4096) {
    src = x; dst = xb; i = bid * 256 + threadIdx.x;
  } else {
    const int z = (bid - 4096) >> 10;
    src = (z == 0) ? w0 : (z == 1) ? w1 : w2;
    dst = Wb + (size_t)z * (1024 * 1024);
    i = ((bid - 4096) & 1023) * 256 + threadIdx.x;
  }
  float4 f = reinterpret_cast<const float4*>(src)[i];
  ushort4 o;
  o.x = f2bf(f.x); o.y = f2bf(f.y); o.z = f2bf(f.z); o.w = f2bf(f.w);
  reinterpret_cast<ushort4*>(dst)[i] = o;
}

// ---------------------------------------------------------------- QKV GEMM
// Main loop unchanged from R8 (proven). Epilogue: Q row-major (unchanged);
// K and V^T now written FRAGMENT-MAJOR (see layout above) with the same or
// better write coalescing (K: 8x128B segs, V: 8x512B segs per pass).
__global__ __launch_bounds__(256, 3) void qkv_gemm(
    const u16* __restrict__ xb, const u16* __restrict__ Wb,
    const float* __restrict__ bq, const float* __restrict__ bk,
    const float* __restrict__ bv,
    u16* __restrict__ Qb, u16* __restrict__ Kb, u16* __restrict__ VTb) {
  __shared__ __attribute__((aligned(16))) u16 smem[2 * 128 * 64];   // 32KB
  u16* As = smem;
  u16* Bs = smem + 128 * 64;

  const int tid = threadIdx.x;
  const int w = tid >> 6, lane = tid & 63;
  const int lo = lane & 15, quad = lane >> 4;
  const int which = blockIdx.z;
  const int m0 = blockIdx.x * 128, n0 = blockIdx.y * 128;

  const u16* W = Wb + (size_t)which * (1024 * 1024);
  const int wm = (w >> 1) * 64, wn = (w & 1) * 64;

  floatx4 acc[4][4];
  for (int i = 0; i < 4; ++i)
    for (int j = 0; j < 4; ++j) acc[i][j] = (floatx4)0.f;

  const int arow = lane >> 3;
  const int aswz = ((lane & 7) ^ arow) * 8;

  for (int kt = 0; kt < 16; ++kt) {
    const int k0 = kt * 64;
    for (int j = 0; j < 4; ++j) {
      const int seg = w * 4 + j;
      glds16(As + seg * 512, xb + (size_t)(m0 + seg * 8 + arow) * 1024 + k0 + aswz);
      glds16(Bs + seg * 512, W + (size_t)(n0 + seg * 8 + arow) * 1024 + k0 + aswz);
    }
    __syncthreads();
    for (int kk = 0; kk < 2; ++kk) {
      const int swz = ((kk * 4 + quad) ^ (lo & 7)) * 8;
      bf16x8 af[4], bfr[4];
      for (int it = 0; it < 4; ++it)
        af[it] = *reinterpret_cast<const bf16x8*>(As + (wm + it * 16 + lo) * 64 + swz);
      for (int jt = 0; jt < 4; ++jt)
        bfr[jt] = *reinterpret_cast<const bf16x8*>(Bs + (wn + jt * 16 + lo) * 64 + swz);
      for (int it = 0; it < 4; ++it)
        for (int jt = 0; jt < 4; ++jt)
          acc[it][jt] = MFMA16(af[it], bfr[jt], acc[it][jt]);
    }
    __syncthreads();
  }

  const float* bias = (which == 0) ? bq : (which == 1) ? bk : bv;
  float bb[4];
  for (int jt = 0; jt < 4; ++jt) bb[jt] = bias[n0 + wn + jt * 16 + lo];
  const int b = m0 >> 11;

  if (which < 2) {
    const float scl = (which == 0) ? 0.36067376022224085f : 1.0f;  // 0.25*log2e
    u16* Tw = smem + w * (16 * 72);
    const int hblk = (n0 + wn) >> 6;
    const int bh = b * 16 + hblk;
    u16* dstQ = Qb + ((size_t)bh * 2048 + ((m0 & 2047) + wm)) * 64;
    u16* dstK = Kb + (size_t)bh * 131072;
    for (int it = 0; it < 4; ++it) {
      for (int jt = 0; jt < 4; ++jt)
        for (int r = 0; r < 4; ++r) {
          const int m = quad * 4 + r, col = jt * 16 + lo;
          Tw[m * 72 + (((col >> 3) ^ (m & 7)) * 8) + (col & 7)] =
              f2bf((acc[it][jt][r] + bb[jt]) * scl);
        }
      MEMFENCE;
      for (int rd = 0; rd < 2; ++rd) {
        const int sr = rd * 8 + (lane >> 3), d8 = lane & 7;
        bf16x8 v = *reinterpret_cast<const bf16x8*>(Tw + sr * 72 + ((d8 ^ (sr & 7)) * 8));
        if (which == 0) {
          *reinterpret_cast<bf16x8*>(dstQ + (size_t)(it * 16 + sr) * 64 + d8 * 8) = v;
        } else {
          const int s = (m0 & 2047) + wm + it * 16 + sr;  // absolute key index
          const size_t idx = (size_t)(s >> 6) * 4096 + (d8 >> 1) * 1024 +
                             ((s >> 5) & 1) * 512 + (d8 & 1) * 256 + (s & 31) * 8;
          *reinterpret_cast<bf16x8*>(dstK + idx) = v;
        }
      }
      MEMFENCE;
    }
  } else {
    for (int pass = 0; pass < 2; ++pass) {
      if ((wm >> 6) == pass) {
        for (int it = 0; it < 4; ++it)
          for (int jt = 0; jt < 4; ++jt)
            for (int r = 0; r < 4; ++r) {
              const int n = wn + jt * 16 + lo;
              const int m = it * 16 + quad * 4 + r;
              smem[n * 72 + (((m >> 3) ^ (n & 7)) * 8) + (m & 7)] =
                  f2bf(acc[it][jt][r] + bb[jt]);
            }
      }
      __syncthreads();
      for (int rd = 0; rd < 4; ++rd) {
        const int n = (tid >> 3) + rd * 32, m8 = tid & 7;
        bf16x8 v = *reinterpret_cast<const bf16x8*>(smem + n * 72 + ((m8 ^ (n & 7)) * 8));
        const int ng = n0 + n, hh = ng >> 6, dloc = ng & 63;
        const int s0 = (m0 & 2047) + pass * 64 + m8 * 8;
        const size_t idx = (size_t)(s0 >> 6) * 4096 + ((s0 >> 4) & 3) * 1024 +
                           (dloc >> 5) * 512 + ((s0 >> 3) & 1) * 256 + (dloc & 31) * 8;
        *reinterpret_cast<bf16x8*>(VTb + (size_t)(b * 16 + hh) * 131072 + idx) = v;
      }
      __syncthreads();
    }
  }
}

// ---------------------------------------------------------------- attention
// 1-wave blocks, NO LDS, NO barriers, NO manual waits. K/V are fragment-major
// so every fragment load is one coalesced 1KB global_load_dwordx4 (fixes
// R10's scattered gathers); compiler tracks vmcnt deps precisely. Register
// double-buffered K/V with dist-1 prefetch issued mid-iteration. 32x32x16
// MFMAs with the R11-HW-verified C-layout + shuffle-based P transform (no
// LDS round trip). 2048 blocks = 8 waves/CU (VGPR-capped 2/SIMD), each an
// independent 32-q tile; qt ascending = longest-first. Fixed-max softmax
// p = exp2(s'). Row 2047 -> lrun==0 -> fix2047.
__global__ __launch_bounds__(64, 2) void attn(
    const u16* __restrict__ Qb, const u16* __restrict__ Kb,
    const u16* __restrict__ VTb, float* __restrict__ out) {
  const int L = blockIdx.x;        // 2048 blocks
  const int bh = L & 31;           // bh%8 = L%8 -> 4 bh per XCD (L2 locality)
  const int qt = L >> 5;           // 0..63 (32-q tiles), ascending = LPT
  const int kstart = qt >> 1;
  const int n = 32 - kstart;

  const int lane = threadIdx.x & 63;
  const int l31 = lane & 31, h = lane >> 5;

  const u16* Qh = Qb + (size_t)bh * (2048 * 64);
  const u16* Kf = Kb + (size_t)bh * 131072;
  const u16* Vf = VTb + (size_t)bh * 131072;

  // Q frags (B-op): B[k = kk*16 + h*8 + j][n = q = l31]
  const int qrow = qt * 32 + l31;
  bf16x8 qf[4];
  for (int kk = 0; kk < 4; ++kk)
    qf[kk] = *reinterpret_cast<const bf16x8*>(Qh + (size_t)qrow * 64 + kk * 16 + h * 8);

  float lrun = 0.f;
  floatx16 acc[2];
  acc[0] = (floatx16)0.f;
  acc[1] = (floatx16)0.f;

#define LOADK(D, kt_)                                                         \
  _Pragma("unroll") for (int ci = 0; ci < 8; ++ci)                            \
      D[ci] = *reinterpret_cast<const bf16x8*>(                               \
          Kf + (size_t)((kt_) * 8 + ci) * 512 + lane * 8);
#define LOADV(D, kt_)                                                         \
  _Pragma("unroll") for (int ci = 0; ci < 8; ++ci)                            \
      D[ci] = *reinterpret_cast<const bf16x8*>(                               \
          Vf + (size_t)((kt_) * 8 + ci) * 512 + lane * 8);

#define ITER(KC, VC, KN, VN)                                                  \
  {                                                                           \
    const int kt = kstart + i;                                                \
    floatx16 sc[2];                                                           \
    sc[0] = (floatx16)0.f;                                                    \
    sc[1] = (floatx16)0.f;                                                    \
    _Pragma("unroll") for (int kk = 0; kk < 4; ++kk)                          \
      _Pragma("unroll") for (int m = 0; m < 2; ++m)                           \
          sc[m] = MFMA32(KC[kk * 2 + m], qf[kk], sc[m]);                      \
    if (i + 1 < n) { LOADK(KN, kt + 1); LOADV(VN, kt + 1); }                  \
    const bool maskp = (i == 0);                                              \
    unsigned pw[2][8];                                                        \
    _Pragma("unroll") for (int m = 0; m < 2; ++m)                             \
      _Pragma("unroll") for (int g = 0; g < 4; ++g) {                         \
        float p0 = EXP2(sc[m][4 * g + 0]), p1 = EXP2(sc[m][4 * g + 1]);       \
        float p2 = EXP2(sc[m][4 * g + 2]), p3 = EXP2(sc[m][4 * g + 3]);       \
        if (maskp) { /* faithful buggy mask: keep key > q */                  \
          const int keyb = kt * 64 + m * 32 + 8 * g + 4 * h;                  \
          p0 = (keyb + 0 > qrow) ? p0 : 0.f;                                  \
          p1 = (keyb + 1 > qrow) ? p1 : 0.f;                                  \
          p2 = (keyb + 2 > qrow) ? p2 : 0.f;                                  \
          p3 = (keyb + 3 > qrow) ? p3 : 0.f;                                  \
        }                                                                     \
        lrun += (p0 + p1) + (p2 + p3);                                        \
        pw[m][2 * g] = pkbf(p0, p1);                                          \
        pw[m][2 * g + 1] = pkbf(p2, p3);                                      \
      }                                                                       \
    unsigned y[2][4];                                                         \
    _Pragma("unroll") for (int m = 0; m < 2; ++m)                             \
      _Pragma("unroll") for (int lh = 0; lh < 2; ++lh)                        \
        _Pragma("unroll") for (int j = 0; j < 2; ++j) {                       \
          const unsigned sv = h ? pw[m][4 * lh + j] : pw[m][4 * lh + 2 + j];  \
          y[m][2 * lh + j] = __shfl_xor(sv, 32);                              \
        }                                                                     \
    bf16x8 pb[4];                                                             \
    _Pragma("unroll") for (int c = 0; c < 4; ++c) {                           \
      const int m = c >> 1, lh = c & 1;                                       \
      uintx4 u;                                                               \
      u.x = h ? y[m][2 * lh]      : pw[m][4 * lh];                            \
      u.y = h ? y[m][2 * lh + 1]  : pw[m][4 * lh + 1];                        \
      u.z = h ? pw[m][4 * lh + 2] : y[m][2 * lh];                             \
      u.w = h ? pw[m][4 * lh + 3] : y[m][2 * lh + 1];                         \
      pb[c] = __builtin_bit_cast(bf16x8, u);                                  \
    }                                                                         \
    _Pragma("unroll") for (int c = 0; c < 4; ++c)                             \
      _Pragma("unroll") for (int dt = 0; dt < 2; ++dt)                        \
          acc[dt] = MFMA32(VC[c * 2 + dt], pb[c], acc[dt]);                   \
    ++i;                                                                      \
  }

  bf16x8 kA[8], vA[8], kB[8], vB[8];
  LOADK(kA, kstart);
  LOADV(vA, kstart);
  int i = 0;
  while (true) {
    ITER(kA, vA, kB, vB);
    if (i >= n) break;
    ITER(kB, vB, kA, vA);
    if (i >= n) break;
  }
#undef ITER
#undef LOADK
#undef LOADV

  lrun += __shfl_xor(lrun, 32);
  if (lrun != 0.f) {   // lrun==0 only for fully-masked row 2047 (fix2047)
    const float rl = 1.f / lrun;
    const int b = bh >> 4, hh = bh & 15;
    float* op = out + ((size_t)(b * 2048 + qrow)) * 1024 + hh * 64;
    for (int dt = 0; dt < 2; ++dt)
      for (int g = 0; g < 4; ++g) {
        float4 o4;   // rows d = dt*32 + 8g + 4h + (0..3)  [R11-verified]
        o4.x = acc[dt][4 * g + 0] * rl;
        o4.y = acc[dt][4 * g + 1] * rl;
        o4.z = acc[dt][4 * g + 2] * rl;
        o4.w = acc[dt][4 * g + 3] * rl;
        *reinterpret_cast<float4*>(op + dt * 32 + 8 * g + 4 * h) = o4;
      }
  }
}

// ---------------------------------------------------------------- fix2047
// Row 2047 fully masked -> uniform softmax: out = mean_s V[b,s,:].
// V is fragment-major: d=(dt,l31) chunks live at kt*4096+c*1024+dt*512+h*256+l31*8.
__global__ __launch_bounds__(256) void fix2047(const u16* __restrict__ VTb,
                                               float* __restrict__ out) {
  const int bh = blockIdx.x;
  const u16* Vh = VTb + (size_t)bh * 131072;
  const int t = threadIdx.x;
  const int d = t >> 2, j = t & 3;        // 4 threads per d, 8 kt each
  const int dt = d >> 5, l31 = d & 31;
  float s = 0.f;
  for (int kt = j * 8; kt < j * 8 + 8; ++kt)
    for (int c = 0; c < 4; ++c)
      for (int h = 0; h < 2; ++h) {
        bf16x8 v = *reinterpret_cast<const bf16x8*>(
            Vh + (size_t)kt * 4096 + c * 1024 + dt * 512 + h * 256 + l31 * 8);
        for (int e = 0; e < 8; ++e) s += bf2f((u16)v[e]);
      }
  s += __shfl_xor(s, 1);
  s += __shfl_xor(s, 2);
  if (j == 0) {
    const int b = bh >> 4, h = bh & 15;
    out[((size_t)(b * 2048 + 2047)) * 1024 + h * 64 + d] = s * (1.f / 2048.f);
  }
}

// ---------------------------------------------------------------- launch
extern "C" void kernel_launch(void* const* d_in, const int* in_sizes, int n_in,
                              void* d_out, int out_size, void* d_ws, size_t ws_size,
                              hipStream_t stream) {
  const float* x  = (const float*)d_in[0];
  const float* Wq = (const float*)d_in[1];
  const float* bq = (const float*)d_in[2];
  const float* Wk = (const float*)d_in[3];
  const float* bk = (const float*)d_in[4];
  const float* Wv = (const float*)d_in[5];
  const float* bv = (const float*)d_in[6];
  float* out = (float*)d_out;

  char* ws = (char*)d_ws;
  u16* xb  = (u16*)(ws);                  // 8 MB: x as bf16 [4096][1024]
  u16* Wb  = (u16*)(ws + (8u << 20));     // 6 MB: Wq,Wk,Wv bf16
  u16* Qb  = (u16*)(ws + (14u << 20));    // 8 MB: Q  [B,H,S,dh] (pre-scaled)
  u16* Kb  = (u16*)(ws + (22u << 20));    // 8 MB: K  fragment-major
  u16* VTb = (u16*)(ws + (30u << 20));    // 8 MB: V  fragment-major

  cvt_all<<<7168, 256, 0, stream>>>(x, Wq, Wk, Wv, xb, Wb);
  qkv_gemm<<<dim3(32, 8, 3), 256, 0, stream>>>(xb, Wb, bq, bk, bv, Qb, Kb, VTb);
  attn<<<dim3(2048), 64, 0, stream>>>(Qb, Kb, VTb, out);
  fix2047<<<dim3(32), 256, 0, stream>>>(VTb, out);
}

// Round 13
// 164.593 us; speedup vs baseline: 1.0072x; 1.0072x over previous
//
#include <hip/hip_runtime.h>
#include <stdint.h>

typedef unsigned short u16;
typedef __attribute__((ext_vector_type(8))) short bf16x8;    // 8 bf16 in 4 VGPRs
typedef __attribute__((ext_vector_type(4))) float floatx4;
typedef __attribute__((ext_vector_type(16))) float floatx16;
typedef __attribute__((ext_vector_type(4))) unsigned uintx4;

#define MFMA16(a, b, c) __builtin_amdgcn_mfma_f32_16x16x32_bf16(a, b, c, 0, 0, 0)
#define MFMA32(a, b, c) __builtin_amdgcn_mfma_f32_32x32x16_bf16(a, b, c, 0, 0, 0)
#define MEMFENCE asm volatile("" ::: "memory")

#if __has_builtin(__builtin_amdgcn_exp2f)
#define EXP2(x) __builtin_amdgcn_exp2f(x)
#else
#define EXP2(x) __expf(0.6931471805599453f * (x))
#endif

__device__ __forceinline__ u16 f2bf(float f) {   // round-to-nearest-even
  unsigned u = __builtin_bit_cast(unsigned, f);
  return (u16)((u + 0x7FFFu + ((u >> 16) & 1u)) >> 16);
}
__device__ __forceinline__ unsigned pkbf(float a, float b) {  // round-half-up pack
  unsigned ua = __builtin_bit_cast(unsigned, a);
  unsigned ub = __builtin_bit_cast(unsigned, b);
  return ((ua + 0x8000u) >> 16) | ((ub + 0x8000u) & 0xFFFF0000u);
}
__device__ __forceinline__ float bf2f(u16 v) {
  return __builtin_bit_cast(float, (unsigned)v << 16);
}

// async global->LDS, 16B/lane. LDS dest = wave-uniform base + lane*16 (HW).
__device__ __forceinline__ void glds16(void* lds, const void* g) {
  __builtin_amdgcn_global_load_lds((const __attribute__((address_space(1))) void*)g,
                                   (__attribute__((address_space(3))) void*)lds,
                                   16, 0, 0);
}

// Fragment-major layouts (u16 strides):
//   Kf[bh][kt][kk][m][h][l31][8]: bh:131072, kt:4096, kk:1024, m:512, h:256, l31:8
//     lane(l31,h) of chunk (kk,m) = K[kt*64 + m*32 + l31][kk*16 + h*8 .. +8]
//   Vf[bh][kt][c][dt][h][l31][8]: bh:131072, kt:4096, c:1024, dt:512, h:256, l31:8
//     lane(l31,h) of chunk (c,dt) = V^T[dt*32 + l31][kt*64 + c*16 + h*8 .. +8]
// => attn fragment load = ONE contiguous 1KB wave read (global_load_dwordx4).

// ---------------------------------------------------------------- convert
__global__ __launch_bounds__(256) void cvt_all(
    const float* __restrict__ x, const float* __restrict__ w0,
    const float* __restrict__ w1, const float* __restrict__ w2,
    u16* __restrict__ xb, u16* __restrict__ Wb) {
  const int bid = blockIdx.x;
  const float* src;
  u16* dst;
  int i;
  if (bid < 4096) {
    src = x; dst = xb; i = bid * 256 + threadIdx.x;
  } else {
    const int z = (bid - 4096) >> 10;
    src = (z == 0) ? w0 : (z == 1) ? w1 : w2;
    dst = Wb + (size_t)z * (1024 * 1024);
    i = ((bid - 4096) & 1023) * 256 + threadIdx.x;
  }
  float4 f = reinterpret_cast<const float4*>(src)[i];
  ushort4 o;
  o.x = f2bf(f.x); o.y = f2bf(f.y); o.z = f2bf(f.z); o.w = f2bf(f.w);
  reinterpret_cast<ushort4*>(dst)[i] = o;
}

// ---------------------------------------------------------------- QKV GEMM
// (unchanged from R12 — proven with fragment-major K/V epilogue.)
__global__ __launch_bounds__(256, 3) void qkv_gemm(
    const u16* __restrict__ xb, const u16* __restrict__ Wb,
    const float* __restrict__ bq, const float* __restrict__ bk,
    const float* __restrict__ bv,
    u16* __restrict__ Qb, u16* __restrict__ Kb, u16* __restrict__ VTb) {
  __shared__ __attribute__((aligned(16))) u16 smem[2 * 128 * 64];   // 32KB
  u16* As = smem;
  u16* Bs = smem + 128 * 64;

  const int tid = threadIdx.x;
  const int w = tid >> 6, lane = tid & 63;
  const int lo = lane & 15, quad = lane >> 4;
  const int which = blockIdx.z;
  const int m0 = blockIdx.x * 128, n0 = blockIdx.y * 128;

  const u16* W = Wb + (size_t)which * (1024 * 1024);
  const int wm = (w >> 1) * 64, wn = (w & 1) * 64;

  floatx4 acc[4][4];
  for (int i = 0; i < 4; ++i)
    for (int j = 0; j < 4; ++j) acc[i][j] = (floatx4)0.f;

  const int arow = lane >> 3;
  const int aswz = ((lane & 7) ^ arow) * 8;

  for (int kt = 0; kt < 16; ++kt) {
    const int k0 = kt * 64;
    for (int j = 0; j < 4; ++j) {
      const int seg = w * 4 + j;
      glds16(As + seg * 512, xb + (size_t)(m0 + seg * 8 + arow) * 1024 + k0 + aswz);
      glds16(Bs + seg * 512, W + (size_t)(n0 + seg * 8 + arow) * 1024 + k0 + aswz);
    }
    __syncthreads();
    for (int kk = 0; kk < 2; ++kk) {
      const int swz = ((kk * 4 + quad) ^ (lo & 7)) * 8;
      bf16x8 af[4], bfr[4];
      for (int it = 0; it < 4; ++it)
        af[it] = *reinterpret_cast<const bf16x8*>(As + (wm + it * 16 + lo) * 64 + swz);
      for (int jt = 0; jt < 4; ++jt)
        bfr[jt] = *reinterpret_cast<const bf16x8*>(Bs + (wn + jt * 16 + lo) * 64 + swz);
      for (int it = 0; it < 4; ++it)
        for (int jt = 0; jt < 4; ++jt)
          acc[it][jt] = MFMA16(af[it], bfr[jt], acc[it][jt]);
    }
    __syncthreads();
  }

  const float* bias = (which == 0) ? bq : (which == 1) ? bk : bv;
  float bb[4];
  for (int jt = 0; jt < 4; ++jt) bb[jt] = bias[n0 + wn + jt * 16 + lo];
  const int b = m0 >> 11;

  if (which < 2) {
    const float scl = (which == 0) ? 0.36067376022224085f : 1.0f;  // 0.25*log2e
    u16* Tw = smem + w * (16 * 72);
    const int hblk = (n0 + wn) >> 6;
    const int bh = b * 16 + hblk;
    u16* dstQ = Qb + ((size_t)bh * 2048 + ((m0 & 2047) + wm)) * 64;
    u16* dstK = Kb + (size_t)bh * 131072;
    for (int it = 0; it < 4; ++it) {
      for (int jt = 0; jt < 4; ++jt)
        for (int r = 0; r < 4; ++r) {
          const int m = quad * 4 + r, col = jt * 16 + lo;
          Tw[m * 72 + (((col >> 3) ^ (m & 7)) * 8) + (col & 7)] =
              f2bf((acc[it][jt][r] + bb[jt]) * scl);
        }
      MEMFENCE;
      for (int rd = 0; rd < 2; ++rd) {
        const int sr = rd * 8 + (lane >> 3), d8 = lane & 7;
        bf16x8 v = *reinterpret_cast<const bf16x8*>(Tw + sr * 72 + ((d8 ^ (sr & 7)) * 8));
        if (which == 0) {
          *reinterpret_cast<bf16x8*>(dstQ + (size_t)(it * 16 + sr) * 64 + d8 * 8) = v;
        } else {
          const int s = (m0 & 2047) + wm + it * 16 + sr;  // absolute key index
          const size_t idx = (size_t)(s >> 6) * 4096 + (d8 >> 1) * 1024 +
                             ((s >> 5) & 1) * 512 + (d8 & 1) * 256 + (s & 31) * 8;
          *reinterpret_cast<bf16x8*>(dstK + idx) = v;
        }
      }
      MEMFENCE;
    }
  } else {
    for (int pass = 0; pass < 2; ++pass) {
      if ((wm >> 6) == pass) {
        for (int it = 0; it < 4; ++it)
          for (int jt = 0; jt < 4; ++jt)
            for (int r = 0; r < 4; ++r) {
              const int n = wn + jt * 16 + lo;
              const int m = it * 16 + quad * 4 + r;
              smem[n * 72 + (((m >> 3) ^ (n & 7)) * 8) + (m & 7)] =
                  f2bf(acc[it][jt][r] + bb[jt]);
            }
      }
      __syncthreads();
      for (int rd = 0; rd < 4; ++rd) {
        const int n = (tid >> 3) + rd * 32, m8 = tid & 7;
        bf16x8 v = *reinterpret_cast<const bf16x8*>(smem + n * 72 + ((m8 ^ (n & 7)) * 8));
        const int ng = n0 + n, hh = ng >> 6, dloc = ng & 63;
        const int s0 = (m0 & 2047) + pass * 64 + m8 * 8;
        const size_t idx = (size_t)(s0 >> 6) * 4096 + ((s0 >> 4) & 3) * 1024 +
                           (dloc >> 5) * 512 + ((s0 >> 3) & 1) * 256 + (dloc & 31) * 8;
        *reinterpret_cast<bf16x8*>(VTb + (size_t)(b * 16 + hh) * 131072 + idx) = v;
      }
      __syncthreads();
    }
  }
}

// ---------------------------------------------------------------- attention
// R12 data path (fragment-major 1KB coalesced loads, 32x32 MFMA, register
// P-transform), despilled + balanced:
//  * K double-buffered (2x32 VGPR) but V SINGLE-buffered, loaded mid-
//    iteration after the QK MFMAs + K-prefetch issue — kills R12's ~31MB/
//    dispatch scratch spill (VGPR budget now ~230 < 256).
//  * Block = pair {qt, 63-qt}, two sequential phases => EVERY block exactly
//    33 iterations; 1024 blocks = steady 4 waves/CU to a common finish (no
//    R12 concurrency decay / tail).
// Fixed-max softmax p = exp2(s'); mask only on each phase's first tile.
// Row 2047 -> lrun==0 -> fix2047.
__global__ __launch_bounds__(64, 2) void attn(
    const u16* __restrict__ Qb, const u16* __restrict__ Kb,
    const u16* __restrict__ VTb, float* __restrict__ out) {
  const int L = blockIdx.x;        // 1024 blocks
  const int bh = L & 31;           // bh%8 = L%8 -> 4 bh per XCD (L2 locality)
  const int j = L >> 5;            // 0..31; pair {j, 63-j} -> 33 iters total

  const int lane = threadIdx.x & 63;
  const int l31 = lane & 31, h = lane >> 5;

  const u16* Qh = Qb + (size_t)bh * (2048 * 64);
  const u16* Kf = Kb + (size_t)bh * 131072;
  const u16* Vf = VTb + (size_t)bh * 131072;
  const int b = bh >> 4, hh = bh & 15;

#define LOADK(D, kt_)                                                         \
  _Pragma("unroll") for (int ci = 0; ci < 8; ++ci)                            \
      D[ci] = *reinterpret_cast<const bf16x8*>(                               \
          Kf + (size_t)((kt_) * 8 + ci) * 512 + lane * 8);
#define LOADV(D, kt_)                                                         \
  _Pragma("unroll") for (int ci = 0; ci < 8; ++ci)                            \
      D[ci] = *reinterpret_cast<const bf16x8*>(                               \
          Vf + (size_t)((kt_) * 8 + ci) * 512 + lane * 8);

  // one iteration: QK from KC; prefetch K(next) into KN; V loaded on demand
#define ITER(KC, KN)                                                          \
  {                                                                           \
    const int kt = kstart + i;                                                \
    floatx16 sc[2];                                                           \
    sc[0] = (floatx16)0.f;                                                    \
    sc[1] = (floatx16)0.f;                                                    \
    _Pragma("unroll") for (int kk = 0; kk < 4; ++kk)                          \
      _Pragma("unroll") for (int m = 0; m < 2; ++m)                           \
          sc[m] = MFMA32(KC[kk * 2 + m], qf[kk], sc[m]);                      \
    bf16x8 vcur[8];                                                           \
    LOADV(vcur, kt);                  /* consumed ~250 cyc later */           \
    if (i + 1 < n) { LOADK(KN, kt + 1); }                                     \
    const bool maskp = (i == 0);                                              \
    unsigned pw[2][8];                                                        \
    _Pragma("unroll") for (int m = 0; m < 2; ++m)                             \
      _Pragma("unroll") for (int g = 0; g < 4; ++g) {                         \
        float p0 = EXP2(sc[m][4 * g + 0]), p1 = EXP2(sc[m][4 * g + 1]);       \
        float p2 = EXP2(sc[m][4 * g + 2]), p3 = EXP2(sc[m][4 * g + 3]);       \
        if (maskp) { /* faithful buggy mask: keep key > q */                  \
          const int keyb = kt * 64 + m * 32 + 8 * g + 4 * h;                  \
          p0 = (keyb + 0 > qrow) ? p0 : 0.f;                                  \
          p1 = (keyb + 1 > qrow) ? p1 : 0.f;                                  \
          p2 = (keyb + 2 > qrow) ? p2 : 0.f;                                  \
          p3 = (keyb + 3 > qrow) ? p3 : 0.f;                                  \
        }                                                                     \
        lrun += (p0 + p1) + (p2 + p3);                                        \
        pw[m][2 * g] = pkbf(p0, p1);                                          \
        pw[m][2 * g + 1] = pkbf(p2, p3);                                      \
      }                                                                       \
    unsigned y[2][4];                                                         \
    _Pragma("unroll") for (int m = 0; m < 2; ++m)                             \
      _Pragma("unroll") for (int lh = 0; lh < 2; ++lh)                        \
        _Pragma("unroll") for (int jj = 0; jj < 2; ++jj) {                    \
          const unsigned sv = h ? pw[m][4 * lh + jj] : pw[m][4 * lh + 2 + jj];\
          y[m][2 * lh + jj] = __shfl_xor(sv, 32);                             \
        }                                                                     \
    _Pragma("unroll") for (int c = 0; c < 4; ++c) {                           \
      const int m = c >> 1, lh = c & 1;                                       \
      uintx4 u;                                                               \
      u.x = h ? y[m][2 * lh]      : pw[m][4 * lh];                            \
      u.y = h ? y[m][2 * lh + 1]  : pw[m][4 * lh + 1];                        \
      u.z = h ? pw[m][4 * lh + 2] : y[m][2 * lh];                             \
      u.w = h ? pw[m][4 * lh + 3] : y[m][2 * lh + 1];                         \
      bf16x8 pb = __builtin_bit_cast(bf16x8, u);                              \
      acc[0] = MFMA32(vcur[c * 2 + 0], pb, acc[0]);                           \
      acc[1] = MFMA32(vcur[c * 2 + 1], pb, acc[1]);                           \
    }                                                                         \
    ++i;                                                                      \
  }

  for (int p = 0; p < 2; ++p) {
    const int qt = (p == 0) ? j : 63 - j;
    const int kstart = qt >> 1;
    const int n = 32 - kstart;

    const int qrow = qt * 32 + l31;
    bf16x8 qf[4];
    for (int kk = 0; kk < 4; ++kk)
      qf[kk] = *reinterpret_cast<const bf16x8*>(Qh + (size_t)qrow * 64 + kk * 16 + h * 8);

    float lrun = 0.f;
    floatx16 acc[2];
    acc[0] = (floatx16)0.f;
    acc[1] = (floatx16)0.f;

    bf16x8 kA[8], kB[8];
    LOADK(kA, kstart);
    int i = 0;
    while (true) {
      ITER(kA, kB);
      if (i >= n) break;
      ITER(kB, kA);
      if (i >= n) break;
    }

    lrun += __shfl_xor(lrun, 32);
    if (lrun != 0.f) {   // lrun==0 only for fully-masked row 2047 (fix2047)
      const float rl = 1.f / lrun;
      float* op = out + ((size_t)(b * 2048 + qrow)) * 1024 + hh * 64;
      for (int dt = 0; dt < 2; ++dt)
        for (int g = 0; g < 4; ++g) {
          float4 o4;   // rows d = dt*32 + 8g + 4h + (0..3)  [R11-verified]
          o4.x = acc[dt][4 * g + 0] * rl;
          o4.y = acc[dt][4 * g + 1] * rl;
          o4.z = acc[dt][4 * g + 2] * rl;
          o4.w = acc[dt][4 * g + 3] * rl;
          *reinterpret_cast<float4*>(op + dt * 32 + 8 * g + 4 * h) = o4;
        }
    }
  }
#undef ITER
#undef LOADK
#undef LOADV
}

// ---------------------------------------------------------------- fix2047
// Row 2047 fully masked -> uniform softmax: out = mean_s V[b,s,:].
// V fragment-major: d=(dt,l31) chunks at kt*4096+c*1024+dt*512+h*256+l31*8.
__global__ __launch_bounds__(256) void fix2047(const u16* __restrict__ VTb,
                                               float* __restrict__ out) {
  const int bh = blockIdx.x;
  const u16* Vh = VTb + (size_t)bh * 131072;
  const int t = threadIdx.x;
  const int d = t >> 2, j = t & 3;        // 4 threads per d, 8 kt each
  const int dt = d >> 5, l31 = d & 31;
  float s = 0.f;
  for (int kt = j * 8; kt < j * 8 + 8; ++kt)
    for (int c = 0; c < 4; ++c)
      for (int h = 0; h < 2; ++h) {
        bf16x8 v = *reinterpret_cast<const bf16x8*>(
            Vh + (size_t)kt * 4096 + c * 1024 + dt * 512 + h * 256 + l31 * 8);
        for (int e = 0; e < 8; ++e) s += bf2f((u16)v[e]);
      }
  s += __shfl_xor(s, 1);
  s += __shfl_xor(s, 2);
  if (j == 0) {
    const int b = bh >> 4, h = bh & 15;
    out[((size_t)(b * 2048 + 2047)) * 1024 + h * 64 + d] = s * (1.f / 2048.f);
  }
}

// ---------------------------------------------------------------- launch
extern "C" void kernel_launch(void* const* d_in, const int* in_sizes, int n_in,
                              void* d_out, int out_size, void* d_ws, size_t ws_size,
                              hipStream_t stream) {
  const float* x  = (const float*)d_in[0];
  const float* Wq = (const float*)d_in[1];
  const float* bq = (const float*)d_in[2];
  const float* Wk = (const float*)d_in[3];
  const float* bk = (const float*)d_in[4];
  const float* Wv = (const float*)d_in[5];
  const float* bv = (const float*)d_in[6];
  float* out = (float*)d_out;

  char* ws = (char*)d_ws;
  u16* xb  = (u16*)(ws);                  // 8 MB: x as bf16 [4096][1024]
  u16* Wb  = (u16*)(ws + (8u << 20));     // 6 MB: Wq,Wk,Wv bf16
  u16* Qb  = (u16*)(ws + (14u << 20));    // 8 MB: Q  [B,H,S,dh] (pre-scaled)
  u16* Kb  = (u16*)(ws + (22u << 20));    // 8 MB: K  fragment-major
  u16* VTb = (u16*)(ws + (30u << 20));    // 8 MB: V  fragment-major

  cvt_all<<<7168, 256, 0, stream>>>(x, Wq, Wk, Wv, xb, Wb);
  qkv_gemm<<<dim3(32, 8, 3), 256, 0, stream>>>(xb, Wb, bq, bk, bv, Qb, Kb, VTb);
  attn<<<dim3(1024), 64, 0, stream>>>(Qb, Kb, VTb, out);
  fix2047<<<dim3(32), 256, 0, stream>>>(VTb, out);
}